// Round 1
// 1311.355 us; speedup vs baseline: 1.5479x; 1.5479x over previous
//
#include <hip/hip_runtime.h>

constexpr int kB = 128;
constexpr int kT = 1024;
constexpr int kI = 64;
constexpr int kH = 512;
constexpr int kO = 32;
constexpr float kTau = 0.2f;
constexpr float kNoise = 0.05f;

__device__ __forceinline__ float fast_tanh(float x) {
    // tanh(x) = 1 - 2/(e^{2x}+1); exact limits at +-inf, ~1e-7 abs error.
    float e = __expf(2.0f * x);
    return 1.0f - 2.0f * __builtin_amdgcn_rcpf(e + 1.0f);
}

// Raw barrier with LDS-only drain: global loads/stores stay in flight across
// it (unlike __syncthreads, which drains vmcnt(0) and serializes prefetches).
#define BARW() do { asm volatile("s_waitcnt lgkmcnt(0)" ::: "memory"); \
                    __builtin_amdgcn_s_barrier();                      \
                    asm volatile("" ::: "memory"); } while (0)

// 64-lane all-reduce add: 5 ds_swizzle xor stages within 32-lane halves,
// one cross-half exchange.
__device__ __forceinline__ float wave_allsum(float s) {
    s += __int_as_float(__builtin_amdgcn_ds_swizzle(__float_as_int(s), 0x041F));
    s += __int_as_float(__builtin_amdgcn_ds_swizzle(__float_as_int(s), 0x081F));
    s += __int_as_float(__builtin_amdgcn_ds_swizzle(__float_as_int(s), 0x101F));
    s += __int_as_float(__builtin_amdgcn_ds_swizzle(__float_as_int(s), 0x201F));
    s += __int_as_float(__builtin_amdgcn_ds_swizzle(__float_as_int(s), 0x401F));
    s += __shfl_xor(s, 32, 64);
    return s;
}

// One block per batch row. 512 threads = one per hidden unit h.
// Per step: phaseA writes 6 rank products; bar; phaseB: waves 0-5 reduce
// columns (strided reads + swizzle butterfly) while ALL waves compute an
// 8-wide i-slice of the input projection (u broadcast is 2 ds_read_b128
// per wave instead of 16 per thread); bar; phaseC combines and updates x.
// noise/u are register-prefetched distance 2 and never drained at barriers.
__global__ __launch_bounds__(512, 2) void scan_kernel(
    const float* __restrict__ u, const float* __restrict__ x0,
    const float* __restrict__ noise, const float* __restrict__ Win_w,
    const float* __restrict__ Win_b, const float* __restrict__ M_rnn,
    const float* __restrict__ N_rnn, const float* __restrict__ L_tb,
    const float* __restrict__ M_tb, const float* __restrict__ N_tb,
    float* __restrict__ traj, float* __restrict__ xfin)
{
    const int b    = blockIdx.x;
    const int h    = threadIdx.x;
    const int wid  = h >> 6;
    const int lane = h & 63;

    __shared__ float red[6 * kH];            // column-major products
    __shared__ float ipp[8 * kH];            // ip partials: [i-slice][h]
    __shared__ __align__(16) float res[8];   // 6 reduced scalars
    __shared__ float u_lds[2][kI];           // double-buffered input row

    // ip-partial weights: this thread covers rows h'=lane+64k, cols isl..isl+7
    const int isl = wid * 8;
    float Wp[8][8];
    #pragma unroll
    for (int k = 0; k < 8; ++k) {
        const float* wr = Win_w + (size_t)(lane + 64 * k) * kI + isl;
        float4 wa = *(const float4*)wr;
        float4 wc = *(const float4*)(wr + 4);
        Wp[k][0] = wa.x; Wp[k][1] = wa.y; Wp[k][2] = wa.z; Wp[k][3] = wa.w;
        Wp[k][4] = wc.x; Wp[k][5] = wc.y; Wp[k][6] = wc.z; Wp[k][7] = wc.w;
    }
    const float wbias = Win_b[h];
    const float Nr0 = N_rnn[h * 2], Nr1 = N_rnn[h * 2 + 1];
    const float Mt0 = M_tb[h * 2],  Mt1 = M_tb[h * 2 + 1];
    const float Nt0 = N_tb[h * 2],  Nt1 = N_tb[h * 2 + 1];
    const float sc_rnn = 1.0f / (float)kH;
    const float sc_tb  = 1.0f / ((float)kH * (float)kH);
    const float Mr0 = M_rnn[h * 2] * sc_rnn, Mr1 = M_rnn[h * 2 + 1] * sc_rnn;
    const float Lt0 = L_tb[h * 2] * sc_tb,   Lt1 = L_tb[h * 2 + 1] * sc_tb;

    float x = x0[b * kH + h];

    const float* up  = u + (size_t)b * kT * kI;
    const float* nzp = noise + (size_t)b * kH + h;     // noise[t][b][h]
    float* tp = traj + (size_t)b * kT * kH + h;        // traj[b][t][h]

    // distance-2 prefetch pipeline (A = even steps, B = odd steps)
    float nzA = nzp[0];
    float nzB = nzp[(size_t)kB * kH];
    float uA = 0.f, uB = 0.f;
    if (wid == 7) {
        u_lds[0][lane] = up[lane];       // stage u[0]
        uA = up[kI + lane];              // u[1], written at C(0)
        uB = up[2 * kI + lane];          // u[2], written at C(1)
    }
    __syncthreads();

    auto step = [&](int t, int par, float& nzC, float& uC) {
        // ---- phase A: rank products ----
        float r = fast_tanh(x);
        red[0 * kH + h] = r * Nr0;
        red[1 * kH + h] = r * Nr1;
        red[2 * kH + h] = r * Mt0;
        red[3 * kH + h] = r * Mt1;
        red[4 * kH + h] = r * Nt0;
        red[5 * kH + h] = r * Nt1;
        BARW();
        // ---- phase B: ip partials (all waves) + column reductions (waves 0-5)
        float4 ua = *(const float4*)&u_lds[par][isl];
        float4 ub = *(const float4*)&u_lds[par][isl + 4];
        #pragma unroll
        for (int k = 0; k < 8; ++k) {
            float p = ua.x * Wp[k][0] + ua.y * Wp[k][1]
                    + ua.z * Wp[k][2] + ua.w * Wp[k][3]
                    + ub.x * Wp[k][4] + ub.y * Wp[k][5]
                    + ub.z * Wp[k][6] + ub.w * Wp[k][7];
            ipp[wid * kH + lane + 64 * k] = p;
        }
        if (wid < 6) {
            const float* c = red + wid * kH + lane;
            float s = c[0] + c[64] + c[128] + c[192] +
                      c[256] + c[320] + c[384] + c[448];
            s = wave_allsum(s);
            if (lane == 0) res[wid] = s;
        }
        BARW();
        // ---- phase C: combine + state update ----
        float4 r4 = *(const float4*)&res[0];   // a0,a1,m0,m1
        float2 r2 = *(const float2*)&res[4];   // n0,n1
        float ip = wbias
                 + ipp[0 * kH + h] + ipp[1 * kH + h]
                 + ipp[2 * kH + h] + ipp[3 * kH + h]
                 + ipp[4 * kH + h] + ipp[5 * kH + h]
                 + ipp[6 * kH + h] + ipp[7 * kH + h];
        float rec = r4.x * Mr0 + r4.y * Mr1
                  + (r4.z * r2.x) * Lt0 + (r4.w * r2.y) * Lt1 + ip;
        x = (1.0f - kTau) * x + kNoise * nzC + kTau * rec;
        tp[(size_t)t * kH] = x;
        // refill prefetch, distance 2 (consumed; reissue into same regs)
        int t2 = (t + 2 < kT) ? t + 2 : kT - 1;
        nzC = nzp[(size_t)t2 * kB * kH];
        if (wid == 7) {
            u_lds[par ^ 1][lane] = uC;   // stage u[t+1]; read after bar1(t+1)
            int t3 = (t + 3 < kT) ? t + 3 : kT - 1;
            uC = up[t3 * kI + lane];
        }
    };

    for (int t = 0; t < kT; t += 2) {
        step(t,     0, nzA, uA);
        step(t + 1, 1, nzB, uB);
    }
    xfin[b * kH + h] = x;
}

// out[row][o] = sum_h tanh(traj[row][h]) * Wout_w[o][h] + Wout_b[o]
// 256 blocks x 256 threads, 2 rows per thread. Wout transposed once into
// LDS [h][o]; inner loop reads are pure same-address broadcasts (conflict
// free), traj rows stream per-thread through L1 as float4. No inner barriers.
__global__ __launch_bounds__(256, 1) void out_kernel(
    const float* __restrict__ traj, const float* __restrict__ Wout_w,
    const float* __restrict__ Wout_b, float* __restrict__ out)
{
    __shared__ float Wl[kH][kO];   // 64 KB, [h][o]
    const int tid = threadIdx.x;
    #pragma unroll
    for (int k = 0; k < 64; ++k) {
        int idx = k * 256 + tid;               // coalesced read
        Wl[idx & (kH - 1)][idx >> 9] = Wout_w[idx];
    }
    __syncthreads();

    const size_t r0 = (size_t)blockIdx.x * 512 + tid;   // rows r0, r0+256
    const float* t0 = traj + r0 * kH;
    const float* t1 = traj + (r0 + 256) * kH;

    float acc0[kO], acc1[kO];
    #pragma unroll
    for (int o = 0; o < kO; ++o) { acc0[o] = 0.f; acc1[o] = 0.f; }

    for (int hh = 0; hh < kH; hh += 4) {
        float4 a4 = *(const float4*)&t0[hh];
        float4 b4 = *(const float4*)&t1[hh];
        float a[4]  = {fast_tanh(a4.x), fast_tanh(a4.y),
                       fast_tanh(a4.z), fast_tanh(a4.w)};
        float bb[4] = {fast_tanh(b4.x), fast_tanh(b4.y),
                       fast_tanh(b4.z), fast_tanh(b4.w)};
        #pragma unroll
        for (int j = 0; j < 4; ++j) {
            #pragma unroll
            for (int o4 = 0; o4 < 8; ++o4) {
                float4 w = *(const float4*)&Wl[hh + j][o4 * 4];
                acc0[o4 * 4 + 0] += a[j] * w.x;  acc1[o4 * 4 + 0] += bb[j] * w.x;
                acc0[o4 * 4 + 1] += a[j] * w.y;  acc1[o4 * 4 + 1] += bb[j] * w.y;
                acc0[o4 * 4 + 2] += a[j] * w.z;  acc1[o4 * 4 + 2] += bb[j] * w.z;
                acc0[o4 * 4 + 3] += a[j] * w.w;  acc1[o4 * 4 + 3] += bb[j] * w.w;
            }
        }
    }

    float* o0 = out + r0 * kO;
    float* o1 = out + (r0 + 256) * kO;
    #pragma unroll
    for (int o4 = 0; o4 < 8; ++o4) {
        float4 bo = *(const float4*)&Wout_b[o4 * 4];
        float4 v0 = {acc0[o4 * 4 + 0] + bo.x, acc0[o4 * 4 + 1] + bo.y,
                     acc0[o4 * 4 + 2] + bo.z, acc0[o4 * 4 + 3] + bo.w};
        float4 v1 = {acc1[o4 * 4 + 0] + bo.x, acc1[o4 * 4 + 1] + bo.y,
                     acc1[o4 * 4 + 2] + bo.z, acc1[o4 * 4 + 3] + bo.w};
        *(float4*)&o0[o4 * 4] = v0;
        *(float4*)&o1[o4 * 4] = v1;
    }
}

extern "C" void kernel_launch(void* const* d_in, const int* in_sizes, int n_in,
                              void* d_out, int out_size, void* d_ws, size_t ws_size,
                              hipStream_t stream) {
    const float* u      = (const float*)d_in[0];
    const float* x0     = (const float*)d_in[1];
    const float* noise  = (const float*)d_in[2];
    const float* Win_w  = (const float*)d_in[3];
    const float* Win_b  = (const float*)d_in[4];
    const float* Wout_w = (const float*)d_in[5];
    const float* Wout_b = (const float*)d_in[6];
    const float* M_rnn  = (const float*)d_in[7];
    const float* N_rnn  = (const float*)d_in[8];
    const float* L_tb   = (const float*)d_in[9];
    const float* M_tb   = (const float*)d_in[10];
    const float* N_tb   = (const float*)d_in[11];

    float* out  = (float*)d_out;                       // [B,T,O]
    float* xfin = out + (size_t)kB * kT * kO;          // [B,H]
    float* traj = xfin + (size_t)kB * kH;              // [B,T,H]

    scan_kernel<<<dim3(kB), dim3(kH), 0, stream>>>(
        u, x0, noise, Win_w, Win_b, M_rnn, N_rnn, L_tb, M_tb, N_tb, traj, xfin);
    out_kernel<<<dim3((kB * kT) / 512), dim3(256), 0, stream>>>(
        traj, Wout_w, Wout_b, out);
}